// Round 7
// baseline (11884.267 us; speedup 1.0000x reference)
//
#include <hip/hip_runtime.h>
#include <math.h>

// ---------------------------------------------------------------------------
// 2-layer LSTM, B=64 T=512 I=256 H=768, fp32 in/out.
// Round 7: persistent kernel; tag-in-data sync, PURE HIP ATOMICS (no inline
// asm). Ring quantum = 8B u64 [f16 h(2u) | f16 h(2u+1) | u32 tag=t+1] stored
// by one relaxed AGENT atomic (co-atomic tag+data). Consumers poll their
// exact quanta subset until all tags match; the poll IS the data load ->
// one L3 round trip per step. Weights in LDS. fp16 MFMA 16x16x32.
// ---------------------------------------------------------------------------

#define B_   64
#define T_   512
#define I_   256
#define H_   768
#define G4H  3072

constexpr size_t BTH = (size_t)B_ * T_ * H_;   // 25165824
constexpr size_t BH  = (size_t)B_ * H_;        // 49152

using f16_t = _Float16;
using f16x8 = __attribute__((ext_vector_type(8))) _Float16;
using f32x4 = __attribute__((ext_vector_type(4))) float;
typedef unsigned long long u64;

#define MFMA(a, b, c) __builtin_amdgcn_mfma_f32_16x16x32_f16((a), (b), (c), 0, 0, 0)

// Ring geometry: u64 quantum (ws, b, pair) at byte ((slot*96+ws)*64+b)*32 + pair*8.
// Producer ws owns units [ws*8, ws*8+8) = 4 pairs.
#define SLOT_STRIDE 196608   // 96*64*32 bytes
#define RING_BYTES  (8 * SLOT_STRIDE)

// LDS partition (bytes): WL 0..98304 | pre 98304..132096 | bsL ..132224
#define SMEM_BYTES 132224

// ---------------------------------------------------------------------------
__global__ void k_packW(const float* __restrict__ src, f16_t* __restrict__ dst,
                        int K, int KC, int total) {
  int i = blockIdx.x * blockDim.x + threadIdx.x;
  int stride = gridDim.x * blockDim.x;
  for (; i < total; i += stride) {
    int e = i & 7;
    int lane = (i >> 3) & 63;
    int rest = i >> 9;          // ptile*KC + kc
    int kc = rest % KC;
    int ptile = rest / KC;
    int p = ptile * 16 + (lane & 15);
    int k = kc * 32 + (lane >> 4) * 8 + e;
    int r = (p & 3) * H_ + (p >> 2);
    dst[i] = (f16_t)src[(size_t)r * K + k];
  }
}

__global__ void k_packX(const float* __restrict__ x, f16_t* __restrict__ dst) {
  int i = blockIdx.x * blockDim.x + threadIdx.x;
  int stride = gridDim.x * blockDim.x;
  const int total = 4 * T_ * 8 * 64 * 8;  // 8,388,608
  for (; i < total; i += stride) {
    int e = i & 7;
    int lane = (i >> 3) & 63;
    int kc = (i >> 9) & 7;
    int t = (i >> 12) & 511;
    int mtile = i >> 21;
    int b = mtile * 16 + (lane & 15);
    int k = kc * 32 + (lane >> 4) * 8 + e;
    dst[i] = (f16_t)x[((size_t)b * T_ + t) * I_ + k];
  }
}

__global__ void k_bias(const float* __restrict__ bih, const float* __restrict__ bhh,
                       float* __restrict__ bsum) {
  int p = blockIdx.x * blockDim.x + threadIdx.x;
  if (p < G4H) {
    int r = (p & 3) * H_ + (p >> 2);
    bsum[p] = bih[r] + bhh[r];
  }
}

__global__ void k_zero(int4* __restrict__ d, int n) {
  int i = blockIdx.x * blockDim.x + threadIdx.x;
  if (i < n) d[i] = make_int4(0, 0, 0, 0);
}

__device__ __forceinline__ float sigf(float v) {
  return __builtin_amdgcn_rcpf(1.0f + __builtin_amdgcn_exp2f(v * -1.44269504f));
}
__device__ __forceinline__ float tanhf_fast(float v) {
  return 2.0f * __builtin_amdgcn_rcpf(1.0f + __builtin_amdgcn_exp2f(v * -2.88539008f)) - 1.0f;
}

__device__ __forceinline__ u64 ld_q(const u64* p) {
  return __hip_atomic_load(p, __ATOMIC_RELAXED, __HIP_MEMORY_SCOPE_AGENT);
}

// Poll KCW chunks (4 u64 quanta each) until every embedded tag == tagv, then
// assemble the A-fragments from the lo-dwords. Stale-tag safety: a tag can
// only equal tagv if that exact 8B store landed (slot tags 8 steps apart).
template <int KCW>
__device__ __forceinline__ void poll_frags(const char* slotbase,
                                           const int (&boff)[KCW],
                                           unsigned tagv, f16x8 (&fr)[KCW]) {
  u64 v[KCW][4];
  for (;;) {
#pragma unroll
    for (int i = 0; i < KCW; ++i) {
      const u64* p = (const u64*)(slotbase + boff[i]);
#pragma unroll
      for (int w = 0; w < 4; ++w) v[i][w] = ld_q(p + w);
    }
    int ok = 1;
#pragma unroll
    for (int i = 0; i < KCW; ++i)
#pragma unroll
      for (int w = 0; w < 4; ++w)
        ok &= (int)((unsigned)(v[i][w] >> 32) == tagv);
    if (__all(ok)) break;
  }
#pragma unroll
  for (int i = 0; i < KCW; ++i) {
    union { unsigned u[4]; f16x8 f; } c;
#pragma unroll
    for (int w = 0; w < 4; ++w) c.u[w] = (unsigned)v[i][w];
    fr[i] = c.f;
  }
}

// ---------------------------------------------------------------------------
// Persistent per-layer loop. 8 waves = mg(2) x kg(4); wave = 2x2 tile
// (mtiles m0,m0+1 x ptiles pt0,pt0+1). W slices in LDS.
// L0: kg0 = x-GEMM (+ mg1: h1[t-8] ring-safety scan); kg1-3 poll h0[t-1].
// L1: kg0-1 poll h0[t]; kg2-3 poll h1[t-1]. Per-mtile poll phases cap VGPRs.
// Intra-layer lockstep (<=1 step skew) is implied: every WG of a layer reads
// ALL 768 units of its layer's h[t-1], so no WG can start step t until all
// 96 WGs published t-1. Only L0-vs-L1 run-ahead (h0 slot reuse after 8
// steps) needs the explicit guard.
template <int KCW, bool IS_L1>
__device__ __forceinline__ void run_layer(
    int ws, const f16_t* __restrict__ Xf, const f16_t* __restrict__ Wihf,
    const f16_t* __restrict__ Whhf, const float* __restrict__ bsum,
    char* __restrict__ ring0c, char* __restrict__ ring1c,
    float* __restrict__ out, char* smem) {
  f16_t* WL = (f16_t*)smem;                              // [4 kg][2 p][KCW][512]
  float (*pre)[64][33] = (float (*)[64][33])(smem + 98304);
  float* bsL = (float*)(smem + 132096);                  // [32]

  const int tid = threadIdx.x;
  const int wave = tid >> 6, lane = tid & 63;
  const int kg = wave & 3, mg = wave >> 2;
  const int laneo = lane * 8;
  const int pt0 = ws * 2, m0 = mg * 2;
  const int l15 = lane & 15, l4 = lane >> 4;

  if (tid < 32) bsL[tid] = bsum[ws * 32 + tid];

  // ---- stage W into LDS (mg==0 waves) ----
  if (mg == 0) {
    const f16_t* src;
    int KC, kc0;
    if constexpr (!IS_L1) {
      if (kg == 0) { src = Wihf; KC = 8;  kc0 = 0; }
      else         { src = Whhf; KC = 24; kc0 = (kg - 1) * 8; }
    } else {
      if (kg < 2)  { src = Wihf; KC = 24; kc0 = kg * 12; }
      else         { src = Whhf; KC = 24; kc0 = (kg - 2) * 12; }
    }
#pragma unroll
    for (int p = 0; p < 2; ++p)
#pragma unroll
      for (int i = 0; i < KCW; ++i)
        *(uint4*)(WL + ((size_t)((kg * 2 + p) * KCW + i)) * 512 + laneo) =
            *(const uint4*)(src + ((size_t)(pt0 + p) * KC + kc0 + i) * 512 + laneo);
  }

  // Consumer chunk start (32-unit chunks of the source h vector).
  int kcs = 0;
  if constexpr (!IS_L1) kcs = (kg - 1) * 8;      // valid for kg>=1
  else                  kcs = (kg < 2) ? kg * 12 : (kg - 2) * 12;

  // Byte offsets within a slot: chunk i, mtile m -> producer ws'=(kcs+i)*4+l4,
  // batch row b = m*16+l15, pairs 0..3 contiguous (32B).
  int boffA[KCW], boffB[KCW];
#pragma unroll
  for (int i = 0; i < KCW; ++i) {
    boffA[i] = ((kcs + i) * 4 + l4) * 2048 + (m0 * 16 + l15) * 32;
    boffB[i] = boffA[i] + 512;   // mtile m0+1
  }

  float c_reg = 0.f;
  const int u = tid & 7, b = tid >> 3;
  const int j = ws * 8 + u;
  char* myringc = IS_L1 ? ring1c : ring0c;
  const f16_t* wl0 = WL + (size_t)(kg * 2) * KCW * 512 + laneo;
  const f16_t* wl1 = wl0 + (size_t)KCW * 512;

  __syncthreads();

  for (int t = 0; t < T_; ++t) {
    f32x4 a00 = {0.f, 0.f, 0.f, 0.f};
    f32x4 a01 = {0.f, 0.f, 0.f, 0.f};
    f32x4 a10 = {0.f, 0.f, 0.f, 0.f};
    f32x4 a11 = {0.f, 0.f, 0.f, 0.f};
    f16x8 fr[KCW];

    if constexpr (!IS_L1) {
      if (kg == 0) {
        // ring-safety: before this WG publishes h0[t] (over h0[t-8]'s slot),
        // all 96 L1 WGs must have finished step t-8 (tag t-7 on h1[t-8]).
        if (mg == 1 && t >= 8) {
          const char* tp = ring1c + (size_t)((t - 8) & 7) * SLOT_STRIDE;
          unsigned want = (unsigned)(t - 7);
          for (;;) {
            unsigned v0 = (unsigned)(ld_q((const u64*)(tp + lane * 2048)) >> 32);
            unsigned v1 = (lane < 32)
                ? (unsigned)(ld_q((const u64*)(tp + (64 + lane) * 2048)) >> 32)
                : want;
            if (__all((v0 == want) & (v1 == want))) break;
            __builtin_amdgcn_s_sleep(1);
          }
        }
        // x_t @ Wih0^T (no recurrence dependency)
        const f16_t* A0 = Xf + ((size_t)m0 * T_ + t) * 4096 + laneo;
        const f16_t* A1 = A0 + (size_t)T_ * 4096;
#pragma unroll
        for (int i = 0; i < KCW; ++i) {
          f16x8 x0 = *(const f16x8*)(A0 + (size_t)i * 512);
          f16x8 x1 = *(const f16x8*)(A1 + (size_t)i * 512);
          f16x8 w0 = *(const f16x8*)(wl0 + (size_t)i * 512);
          f16x8 w1 = *(const f16x8*)(wl1 + (size_t)i * 512);
          a00 = MFMA(x0, w0, a00);
          a01 = MFMA(x0, w1, a01);
          a10 = MFMA(x1, w0, a10);
          a11 = MFMA(x1, w1, a11);
        }
      } else if (t >= 1) {
        const char* sb = ring0c + (size_t)((t - 1) & 7) * SLOT_STRIDE;
        poll_frags<KCW>(sb, boffA, (unsigned)t, fr);
#pragma unroll
        for (int i = 0; i < KCW; ++i) {
          f16x8 w0 = *(const f16x8*)(wl0 + (size_t)i * 512);
          f16x8 w1 = *(const f16x8*)(wl1 + (size_t)i * 512);
          a00 = MFMA(fr[i], w0, a00);
          a01 = MFMA(fr[i], w1, a01);
        }
        poll_frags<KCW>(sb, boffB, (unsigned)t, fr);
#pragma unroll
        for (int i = 0; i < KCW; ++i) {
          f16x8 w0 = *(const f16x8*)(wl0 + (size_t)i * 512);
          f16x8 w1 = *(const f16x8*)(wl1 + (size_t)i * 512);
          a10 = MFMA(fr[i], w0, a10);
          a11 = MFMA(fr[i], w1, a11);
        }
      }
    } else {
      const int srcstep = (kg < 2) ? t : t - 1;
      if (srcstep >= 0) {
        const char* sb = ((kg < 2) ? ring0c : ring1c) +
                         (size_t)(srcstep & 7) * SLOT_STRIDE;
        const unsigned tg = (unsigned)(srcstep + 1);
        poll_frags<KCW>(sb, boffA, tg, fr);
#pragma unroll
        for (int i = 0; i < KCW; ++i) {
          f16x8 w0 = *(const f16x8*)(wl0 + (size_t)i * 512);
          f16x8 w1 = *(const f16x8*)(wl1 + (size_t)i * 512);
          a00 = MFMA(fr[i], w0, a00);
          a01 = MFMA(fr[i], w1, a01);
        }
        poll_frags<KCW>(sb, boffB, tg, fr);
#pragma unroll
        for (int i = 0; i < KCW; ++i) {
          f16x8 w0 = *(const f16x8*)(wl0 + (size_t)i * 512);
          f16x8 w1 = *(const f16x8*)(wl1 + (size_t)i * 512);
          a10 = MFMA(fr[i], w0, a10);
          a11 = MFMA(fr[i], w1, a11);
        }
      }
    }

    // ---- partial-sum exchange (C layout: col=lane&15, row=l4*4+r) ----
#pragma unroll
    for (int r = 0; r < 4; ++r) {
      pre[kg][m0 * 16 + l4 * 4 + r][l15]           = a00[r];
      pre[kg][m0 * 16 + l4 * 4 + r][16 + l15]      = a01[r];
      pre[kg][m0 * 16 + 16 + l4 * 4 + r][l15]      = a10[r];
      pre[kg][m0 * 16 + 16 + l4 * 4 + r][16 + l15] = a11[r];
    }
    __syncthreads();

    // ---- gate phase: thread = (u = tid&7, b = tid>>3) ----
    {
      float g0 = pre[0][b][4 * u + 0] + pre[1][b][4 * u + 0] + pre[2][b][4 * u + 0] + pre[3][b][4 * u + 0] + bsL[4 * u + 0];
      float g1 = pre[0][b][4 * u + 1] + pre[1][b][4 * u + 1] + pre[2][b][4 * u + 1] + pre[3][b][4 * u + 1] + bsL[4 * u + 1];
      float g2 = pre[0][b][4 * u + 2] + pre[1][b][4 * u + 2] + pre[2][b][4 * u + 2] + pre[3][b][4 * u + 2] + bsL[4 * u + 2];
      float g3 = pre[0][b][4 * u + 3] + pre[1][b][4 * u + 3] + pre[2][b][4 * u + 3] + pre[3][b][4 * u + 3] + bsL[4 * u + 3];
      float ig = sigf(g0), fg = sigf(g1), gg = tanhf_fast(g2), og = sigf(g3);
      c_reg = fg * c_reg + ig * gg;
      float h = og * tanhf_fast(c_reg);

      // publish FIRST (critical path): even-u threads store one u64 quantum
      // [h(u) | h(u+1) | tag=t+1] with a single co-atomic relaxed store.
      unsigned hb = (unsigned)__builtin_bit_cast(unsigned short, (f16_t)h);
      unsigned nb = (unsigned)__shfl((int)hb, lane + 1);
      if ((u & 1) == 0) {
        u64 val = (u64)(hb | (nb << 16)) | ((u64)(unsigned)(t + 1) << 32);
        u64* dst = (u64*)(myringc + (size_t)(t & 7) * SLOT_STRIDE +
                          (size_t)ws * 2048 + (size_t)b * 32 + (u >> 1) * 8);
        __hip_atomic_store(dst, val, __ATOMIC_RELAXED, __HIP_MEMORY_SCOPE_AGENT);
      }

      if constexpr (IS_L1) {
        out[((size_t)b * T_ + t) * H_ + j] = h;  // ys
        if (t == T_ - 1) {
          out[BTH + BH + (size_t)b * H_ + j] = h;
          out[BTH + 3 * BH + (size_t)b * H_ + j] = c_reg;
        }
      } else {
        if (t == T_ - 1) {
          out[BTH + (size_t)b * H_ + j] = h;
          out[BTH + 2 * BH + (size_t)b * H_ + j] = c_reg;
        }
      }
    }
    __syncthreads();   // pre[] of t+1 must not race gate reads of t
  }
}

__launch_bounds__(512, 2)
__global__ void k_lstm(const f16_t* __restrict__ Xf,
                       const f16_t* __restrict__ Wih0f, const f16_t* __restrict__ Whh0f,
                       const f16_t* __restrict__ Wih1f, const f16_t* __restrict__ Whh1f,
                       const float* __restrict__ bsum0, const float* __restrict__ bsum1,
                       char* __restrict__ ring0c, char* __restrict__ ring1c,
                       float* __restrict__ out) {
  extern __shared__ char smem[];
  const int wg = blockIdx.x;
  if (wg < 96)
    run_layer<8, false>(wg, Xf, Wih0f, Whh0f, bsum0, ring0c, ring1c, out, smem);
  else
    run_layer<12, true>(wg - 96, Xf, Wih1f, Whh1f, bsum1, ring0c, ring1c, out, smem);
}

// ---------------------------------------------------------------------------
extern "C" void kernel_launch(void* const* d_in, const int* in_sizes, int n_in,
                              void* d_out, int out_size, void* d_ws, size_t ws_size,
                              hipStream_t stream) {
  const float* x    = (const float*)d_in[0];
  const float* wih0 = (const float*)d_in[1];
  const float* whh0 = (const float*)d_in[2];
  const float* bih0 = (const float*)d_in[3];
  const float* bhh0 = (const float*)d_in[4];
  const float* wih1 = (const float*)d_in[5];
  const float* whh1 = (const float*)d_in[6];
  const float* bih1 = (const float*)d_in[7];
  const float* bhh1 = (const float*)d_in[8];
  float* out = (float*)d_out;

  char* base = (char*)d_ws;
  size_t off = 0;
  auto take = [&](size_t bytes) -> char* {
    char* r = base + off;
    off = (off + bytes + 255) & ~(size_t)255;
    return r;
  };
  f16_t* Wih0f = (f16_t*)take((size_t)G4H * I_ * 2);
  f16_t* Whh0f = (f16_t*)take((size_t)G4H * H_ * 2);
  f16_t* Wih1f = (f16_t*)take((size_t)G4H * H_ * 2);
  f16_t* Whh1f = (f16_t*)take((size_t)G4H * H_ * 2);
  f16_t* Xf    = (f16_t*)take((size_t)4 * T_ * 8 * 64 * 8 * 2);
  float* bsum0 = (float*)take((size_t)G4H * 4);
  float* bsum1 = (float*)take((size_t)G4H * 4);
  // state (zeroed each call): 2 tagged rings, 8 slots each
  const size_t stateBytes = 2 * (size_t)RING_BYTES;   // 3,145,728
  char* st = take(stateBytes);
  char* ring0c = st;
  char* ring1c = st + RING_BYTES;

  hipFuncSetAttribute(reinterpret_cast<const void*>(k_lstm),
                      hipFuncAttributeMaxDynamicSharedMemorySize, SMEM_BYTES);

  k_packW<<<768, 256, 0, stream>>>(wih0, Wih0f, I_, 8, G4H * I_);
  k_packW<<<2048, 256, 0, stream>>>(whh0, Whh0f, H_, 24, G4H * H_);
  k_packW<<<2048, 256, 0, stream>>>(wih1, Wih1f, H_, 24, G4H * H_);
  k_packW<<<2048, 256, 0, stream>>>(whh1, Whh1f, H_, 24, G4H * H_);
  k_packX<<<4096, 256, 0, stream>>>(x, Xf);
  k_bias<<<12, 256, 0, stream>>>(bih0, bhh0, bsum0);
  k_bias<<<12, 256, 0, stream>>>(bih1, bhh1, bsum1);
  k_zero<<<768, 256, 0, stream>>>((int4*)st, (int)(stateBytes / 16));

  k_lstm<<<192, 512, SMEM_BYTES, stream>>>(Xf, Wih0f, Whh0f, Wih1f, Whh1f,
                                           bsum0, bsum1, ring0c, ring1c, out);
}

// Round 8
// 10189.250 us; speedup vs baseline: 1.1664x; 1.1664x over previous
//
#include <hip/hip_runtime.h>
#include <math.h>

// ---------------------------------------------------------------------------
// 2-layer LSTM, B=64 T=512 I=256 H=768, fp32 in/out.
// Round 8: persistent kernel; tag-in-data sync with round-5 traffic
// discipline. Producer: ONE u64 atomic store per quantum [2xf16 | tag=t+1]
// (no vmcnt, no flags). Consumer: narrow 4B tag poll (detect) -> one
// combined u64 burst for all A+B fragments, validated by embedded tags
// (rare retry). Agent atomics appear once per step, never wide-in-a-loop.
// Weights in LDS. fp16 MFMA 16x16x32.
// ---------------------------------------------------------------------------

#define B_   64
#define T_   512
#define I_   256
#define H_   768
#define G4H  3072

constexpr size_t BTH = (size_t)B_ * T_ * H_;   // 25165824
constexpr size_t BH  = (size_t)B_ * H_;        // 49152

using f16_t = _Float16;
using f16x8 = __attribute__((ext_vector_type(8))) _Float16;
using f32x4 = __attribute__((ext_vector_type(4))) float;
typedef unsigned long long u64;

#define MFMA(a, b, c) __builtin_amdgcn_mfma_f32_16x16x32_f16((a), (b), (c), 0, 0, 0)

// Ring geometry: u64 quantum (ws, b, pair) at byte ((slot*96+ws)*64+b)*32 + pair*8.
#define SLOT_STRIDE 196608   // 96*64*32 bytes
#define RING_BYTES  (8 * SLOT_STRIDE)

// LDS partition (bytes): WL 0..98304 | pre 98304..132096 | bsL ..132224
#define SMEM_BYTES 132224

// ---------------------------------------------------------------------------
__global__ void k_packW(const float* __restrict__ src, f16_t* __restrict__ dst,
                        int K, int KC, int total) {
  int i = blockIdx.x * blockDim.x + threadIdx.x;
  int stride = gridDim.x * blockDim.x;
  for (; i < total; i += stride) {
    int e = i & 7;
    int lane = (i >> 3) & 63;
    int rest = i >> 9;          // ptile*KC + kc
    int kc = rest % KC;
    int ptile = rest / KC;
    int p = ptile * 16 + (lane & 15);
    int k = kc * 32 + (lane >> 4) * 8 + e;
    int r = (p & 3) * H_ + (p >> 2);
    dst[i] = (f16_t)src[(size_t)r * K + k];
  }
}

__global__ void k_packX(const float* __restrict__ x, f16_t* __restrict__ dst) {
  int i = blockIdx.x * blockDim.x + threadIdx.x;
  int stride = gridDim.x * blockDim.x;
  const int total = 4 * T_ * 8 * 64 * 8;  // 8,388,608
  for (; i < total; i += stride) {
    int e = i & 7;
    int lane = (i >> 3) & 63;
    int kc = (i >> 9) & 7;
    int t = (i >> 12) & 511;
    int mtile = i >> 21;
    int b = mtile * 16 + (lane & 15);
    int k = kc * 32 + (lane >> 4) * 8 + e;
    dst[i] = (f16_t)x[((size_t)b * T_ + t) * I_ + k];
  }
}

__global__ void k_bias(const float* __restrict__ bih, const float* __restrict__ bhh,
                       float* __restrict__ bsum) {
  int p = blockIdx.x * blockDim.x + threadIdx.x;
  if (p < G4H) {
    int r = (p & 3) * H_ + (p >> 2);
    bsum[p] = bih[r] + bhh[r];
  }
}

__global__ void k_zero(int4* __restrict__ d, int n) {
  int i = blockIdx.x * blockDim.x + threadIdx.x;
  if (i < n) d[i] = make_int4(0, 0, 0, 0);
}

__device__ __forceinline__ float sigf(float v) {
  return __builtin_amdgcn_rcpf(1.0f + __builtin_amdgcn_exp2f(v * -1.44269504f));
}
__device__ __forceinline__ float tanhf_fast(float v) {
  return 2.0f * __builtin_amdgcn_rcpf(1.0f + __builtin_amdgcn_exp2f(v * -2.88539008f)) - 1.0f;
}

__device__ __forceinline__ u64 ld_q(const u64* p) {
  return __hip_atomic_load(p, __ATOMIC_RELAXED, __HIP_MEMORY_SCOPE_AGENT);
}
__device__ __forceinline__ unsigned ld_tag(const void* p) {
  return __hip_atomic_load((const unsigned*)p, __ATOMIC_RELAXED,
                           __HIP_MEMORY_SCOPE_AGENT);
}

// Narrow detect: poll only the 4B tag dword of each A-phase quantum-0.
template <int KCW>
__device__ __forceinline__ void wait_tags(const char* sb, const int (&boff)[KCW],
                                          unsigned tagv) {
  for (;;) {
    int ok = 1;
#pragma unroll
    for (int i = 0; i < KCW; ++i)
      ok &= (int)(ld_tag(sb + boff[i] + 4) == tagv);
    if (__all(ok)) return;
    __builtin_amdgcn_s_sleep(2);
  }
}

// One combined burst: all A+B quanta (2*KCW chunks x 4 u64), validate every
// embedded tag (rare retry -- detect already confirmed producers), then
// convert + MFMA. Stale-tag safety: tag==tagv <=> that exact 8B store landed
// (slot tags 8 steps apart).
template <int KCW>
__device__ __forceinline__ void load2_mfma(const char* sb, const int (&bA)[KCW],
                                           const int (&bB)[KCW], unsigned tagv,
                                           const f16_t* wl0, const f16_t* wl1,
                                           f32x4& a00, f32x4& a01, f32x4& a10,
                                           f32x4& a11) {
  u64 v[2][KCW][4];
  for (;;) {
#pragma unroll
    for (int i = 0; i < KCW; ++i) {
      const u64* pA = (const u64*)(sb + bA[i]);
      const u64* pB = (const u64*)(sb + bB[i]);
#pragma unroll
      for (int w = 0; w < 4; ++w) {
        v[0][i][w] = ld_q(pA + w);
        v[1][i][w] = ld_q(pB + w);
      }
    }
    int ok = 1;
#pragma unroll
    for (int h = 0; h < 2; ++h)
#pragma unroll
      for (int i = 0; i < KCW; ++i)
#pragma unroll
        for (int w = 0; w < 4; ++w)
          ok &= (int)((unsigned)(v[h][i][w] >> 32) == tagv);
    if (__all(ok)) break;
    __builtin_amdgcn_s_sleep(2);
  }
#pragma unroll
  for (int i = 0; i < KCW; ++i) {
    union { unsigned u[4]; f16x8 f; } cA, cB;
#pragma unroll
    for (int w = 0; w < 4; ++w) {
      cA.u[w] = (unsigned)v[0][i][w];
      cB.u[w] = (unsigned)v[1][i][w];
    }
    f16x8 w0 = *(const f16x8*)(wl0 + (size_t)i * 512);
    f16x8 w1 = *(const f16x8*)(wl1 + (size_t)i * 512);
    a00 = MFMA(cA.f, w0, a00);
    a01 = MFMA(cA.f, w1, a01);
    a10 = MFMA(cB.f, w0, a10);
    a11 = MFMA(cB.f, w1, a11);
  }
}

// ---------------------------------------------------------------------------
// Persistent per-layer loop. 8 waves = mg(2) x kg(4); wave = 2x2 tile.
// L0: kg0 = x-GEMM (+ mg1: h1[t-8] ring-safety scan); kg1-3 consume h0[t-1].
// L1: kg0-1 consume h0[t]; kg2-3 consume h1[t-1].
// Intra-layer lockstep (<=1 step skew) implied by the full h broadcast; only
// L0-vs-L1 run-ahead (h0 slot reuse at depth 8) needs the explicit guard.
template <int KCW, bool IS_L1>
__device__ __forceinline__ void run_layer(
    int ws, const f16_t* __restrict__ Xf, const f16_t* __restrict__ Wihf,
    const f16_t* __restrict__ Whhf, const float* __restrict__ bsum,
    char* __restrict__ ring0c, char* __restrict__ ring1c,
    float* __restrict__ out, char* smem) {
  f16_t* WL = (f16_t*)smem;                              // [4 kg][2 p][KCW][512]
  float (*pre)[64][33] = (float (*)[64][33])(smem + 98304);
  float* bsL = (float*)(smem + 132096);                  // [32]

  const int tid = threadIdx.x;
  const int wave = tid >> 6, lane = tid & 63;
  const int kg = wave & 3, mg = wave >> 2;
  const int laneo = lane * 8;
  const int pt0 = ws * 2, m0 = mg * 2;
  const int l15 = lane & 15, l4 = lane >> 4;

  if (tid < 32) bsL[tid] = bsum[ws * 32 + tid];

  // ---- stage W into LDS (mg==0 waves) ----
  if (mg == 0) {
    const f16_t* src;
    int KC, kc0;
    if constexpr (!IS_L1) {
      if (kg == 0) { src = Wihf; KC = 8;  kc0 = 0; }
      else         { src = Whhf; KC = 24; kc0 = (kg - 1) * 8; }
    } else {
      if (kg < 2)  { src = Wihf; KC = 24; kc0 = kg * 12; }
      else         { src = Whhf; KC = 24; kc0 = (kg - 2) * 12; }
    }
#pragma unroll
    for (int p = 0; p < 2; ++p)
#pragma unroll
      for (int i = 0; i < KCW; ++i)
        *(uint4*)(WL + ((size_t)((kg * 2 + p) * KCW + i)) * 512 + laneo) =
            *(const uint4*)(src + ((size_t)(pt0 + p) * KC + kc0 + i) * 512 + laneo);
  }

  // Consumer chunk start (32-unit chunks of the source h vector).
  int kcs = 0;
  if constexpr (!IS_L1) kcs = (kg - 1) * 8;      // valid for kg>=1
  else                  kcs = (kg < 2) ? kg * 12 : (kg - 2) * 12;

  // Byte offsets within a slot: chunk i, mtile m -> producer ws'=(kcs+i)*4+l4,
  // batch row b = m*16+l15, pairs 0..3 contiguous (32B).
  int boffA[KCW], boffB[KCW];
#pragma unroll
  for (int i = 0; i < KCW; ++i) {
    boffA[i] = ((kcs + i) * 4 + l4) * 2048 + (m0 * 16 + l15) * 32;
    boffB[i] = boffA[i] + 512;   // mtile m0+1
  }

  float c_reg = 0.f;
  const int u = tid & 7, b = tid >> 3;
  const int j = ws * 8 + u;
  char* myringc = IS_L1 ? ring1c : ring0c;
  const f16_t* wl0 = WL + (size_t)(kg * 2) * KCW * 512 + laneo;
  const f16_t* wl1 = wl0 + (size_t)KCW * 512;

  __syncthreads();

  for (int t = 0; t < T_; ++t) {
    f32x4 a00 = {0.f, 0.f, 0.f, 0.f};
    f32x4 a01 = {0.f, 0.f, 0.f, 0.f};
    f32x4 a10 = {0.f, 0.f, 0.f, 0.f};
    f32x4 a11 = {0.f, 0.f, 0.f, 0.f};

    if constexpr (!IS_L1) {
      if (kg == 0) {
        // ring-safety: before this WG publishes h0[t] (over h0[t-8]'s slot),
        // all 96 L1 WGs must have started publishing step t-8 (tag t-7 on
        // h1[t-8]) -- which implies they consumed h0[t-8].
        if (mg == 1 && t >= 8) {
          const char* tp = ring1c + (size_t)((t - 8) & 7) * SLOT_STRIDE + 4;
          unsigned want = (unsigned)(t - 7);
          for (;;) {
            unsigned v0 = ld_tag(tp + lane * 2048);
            unsigned v1 = (lane < 32) ? ld_tag(tp + (64 + lane) * 2048) : want;
            if (__all((v0 == want) & (v1 == want))) break;
            __builtin_amdgcn_s_sleep(2);
          }
        }
        // x_t @ Wih0^T (no recurrence dependency)
        const f16_t* A0 = Xf + ((size_t)m0 * T_ + t) * 4096 + laneo;
        const f16_t* A1 = A0 + (size_t)T_ * 4096;
#pragma unroll
        for (int i = 0; i < KCW; ++i) {
          f16x8 x0 = *(const f16x8*)(A0 + (size_t)i * 512);
          f16x8 x1 = *(const f16x8*)(A1 + (size_t)i * 512);
          f16x8 w0 = *(const f16x8*)(wl0 + (size_t)i * 512);
          f16x8 w1 = *(const f16x8*)(wl1 + (size_t)i * 512);
          a00 = MFMA(x0, w0, a00);
          a01 = MFMA(x0, w1, a01);
          a10 = MFMA(x1, w0, a10);
          a11 = MFMA(x1, w1, a11);
        }
      } else if (t >= 1) {
        const char* sb = ring0c + (size_t)((t - 1) & 7) * SLOT_STRIDE;
        wait_tags<KCW>(sb, boffA, (unsigned)t);
        load2_mfma<KCW>(sb, boffA, boffB, (unsigned)t, wl0, wl1, a00, a01, a10, a11);
      }
    } else {
      const int srcstep = (kg < 2) ? t : t - 1;
      if (srcstep >= 0) {
        const char* sb = ((kg < 2) ? ring0c : ring1c) +
                         (size_t)(srcstep & 7) * SLOT_STRIDE;
        const unsigned tg = (unsigned)(srcstep + 1);
        wait_tags<KCW>(sb, boffA, tg);
        load2_mfma<KCW>(sb, boffA, boffB, tg, wl0, wl1, a00, a01, a10, a11);
      }
    }

    // ---- partial-sum exchange (C layout: col=lane&15, row=l4*4+r) ----
#pragma unroll
    for (int r = 0; r < 4; ++r) {
      pre[kg][m0 * 16 + l4 * 4 + r][l15]           = a00[r];
      pre[kg][m0 * 16 + l4 * 4 + r][16 + l15]      = a01[r];
      pre[kg][m0 * 16 + 16 + l4 * 4 + r][l15]      = a10[r];
      pre[kg][m0 * 16 + 16 + l4 * 4 + r][16 + l15] = a11[r];
    }
    __syncthreads();

    // ---- gate phase: thread = (u = tid&7, b = tid>>3) ----
    {
      float g0 = pre[0][b][4 * u + 0] + pre[1][b][4 * u + 0] + pre[2][b][4 * u + 0] + pre[3][b][4 * u + 0] + bsL[4 * u + 0];
      float g1 = pre[0][b][4 * u + 1] + pre[1][b][4 * u + 1] + pre[2][b][4 * u + 1] + pre[3][b][4 * u + 1] + bsL[4 * u + 1];
      float g2 = pre[0][b][4 * u + 2] + pre[1][b][4 * u + 2] + pre[2][b][4 * u + 2] + pre[3][b][4 * u + 2] + bsL[4 * u + 2];
      float g3 = pre[0][b][4 * u + 3] + pre[1][b][4 * u + 3] + pre[2][b][4 * u + 3] + pre[3][b][4 * u + 3] + bsL[4 * u + 3];
      float ig = sigf(g0), fg = sigf(g1), gg = tanhf_fast(g2), og = sigf(g3);
      c_reg = fg * c_reg + ig * gg;
      float h = og * tanhf_fast(c_reg);

      // publish FIRST (critical path): even-u threads store one u64 quantum
      // [h(u) | h(u+1) | tag=t+1] with a single co-atomic relaxed store.
      unsigned hb = (unsigned)__builtin_bit_cast(unsigned short, (f16_t)h);
      unsigned nb = (unsigned)__shfl((int)hb, lane + 1);
      if ((u & 1) == 0) {
        u64 val = (u64)(hb | (nb << 16)) | ((u64)(unsigned)(t + 1) << 32);
        u64* dst = (u64*)(myringc + (size_t)(t & 7) * SLOT_STRIDE +
                          (size_t)ws * 2048 + (size_t)b * 32 + (u >> 1) * 8);
        __hip_atomic_store(dst, val, __ATOMIC_RELAXED, __HIP_MEMORY_SCOPE_AGENT);
      }

      if constexpr (IS_L1) {
        out[((size_t)b * T_ + t) * H_ + j] = h;  // ys
        if (t == T_ - 1) {
          out[BTH + BH + (size_t)b * H_ + j] = h;
          out[BTH + 3 * BH + (size_t)b * H_ + j] = c_reg;
        }
      } else {
        if (t == T_ - 1) {
          out[BTH + (size_t)b * H_ + j] = h;
          out[BTH + 2 * BH + (size_t)b * H_ + j] = c_reg;
        }
      }
    }
    __syncthreads();   // pre[] of t+1 must not race gate reads of t
  }
}

__launch_bounds__(512, 1)
__global__ void k_lstm(const f16_t* __restrict__ Xf,
                       const f16_t* __restrict__ Wih0f, const f16_t* __restrict__ Whh0f,
                       const f16_t* __restrict__ Wih1f, const f16_t* __restrict__ Whh1f,
                       const float* __restrict__ bsum0, const float* __restrict__ bsum1,
                       char* __restrict__ ring0c, char* __restrict__ ring1c,
                       float* __restrict__ out) {
  extern __shared__ char smem[];
  const int wg = blockIdx.x;
  if (wg < 96)
    run_layer<8, false>(wg, Xf, Wih0f, Whh0f, bsum0, ring0c, ring1c, out, smem);
  else
    run_layer<12, true>(wg - 96, Xf, Wih1f, Whh1f, bsum1, ring0c, ring1c, out, smem);
}

// ---------------------------------------------------------------------------
extern "C" void kernel_launch(void* const* d_in, const int* in_sizes, int n_in,
                              void* d_out, int out_size, void* d_ws, size_t ws_size,
                              hipStream_t stream) {
  const float* x    = (const float*)d_in[0];
  const float* wih0 = (const float*)d_in[1];
  const float* whh0 = (const float*)d_in[2];
  const float* bih0 = (const float*)d_in[3];
  const float* bhh0 = (const float*)d_in[4];
  const float* wih1 = (const float*)d_in[5];
  const float* whh1 = (const float*)d_in[6];
  const float* bih1 = (const float*)d_in[7];
  const float* bhh1 = (const float*)d_in[8];
  float* out = (float*)d_out;

  char* base = (char*)d_ws;
  size_t off = 0;
  auto take = [&](size_t bytes) -> char* {
    char* r = base + off;
    off = (off + bytes + 255) & ~(size_t)255;
    return r;
  };
  f16_t* Wih0f = (f16_t*)take((size_t)G4H * I_ * 2);
  f16_t* Whh0f = (f16_t*)take((size_t)G4H * H_ * 2);
  f16_t* Wih1f = (f16_t*)take((size_t)G4H * H_ * 2);
  f16_t* Whh1f = (f16_t*)take((size_t)G4H * H_ * 2);
  f16_t* Xf    = (f16_t*)take((size_t)4 * T_ * 8 * 64 * 8 * 2);
  float* bsum0 = (float*)take((size_t)G4H * 4);
  float* bsum1 = (float*)take((size_t)G4H * 4);
  // state (zeroed each call): 2 tagged rings, 8 slots each
  const size_t stateBytes = 2 * (size_t)RING_BYTES;   // 3,145,728
  char* st = take(stateBytes);
  char* ring0c = st;
  char* ring1c = st + RING_BYTES;

  hipFuncSetAttribute(reinterpret_cast<const void*>(k_lstm),
                      hipFuncAttributeMaxDynamicSharedMemorySize, SMEM_BYTES);

  k_packW<<<768, 256, 0, stream>>>(wih0, Wih0f, I_, 8, G4H * I_);
  k_packW<<<2048, 256, 0, stream>>>(whh0, Whh0f, H_, 24, G4H * H_);
  k_packW<<<2048, 256, 0, stream>>>(wih1, Wih1f, H_, 24, G4H * H_);
  k_packW<<<2048, 256, 0, stream>>>(whh1, Whh1f, H_, 24, G4H * H_);
  k_packX<<<4096, 256, 0, stream>>>(x, Xf);
  k_bias<<<12, 256, 0, stream>>>(bih0, bhh0, bsum0);
  k_bias<<<12, 256, 0, stream>>>(bih1, bhh1, bsum1);
  k_zero<<<768, 256, 0, stream>>>((int4*)st, (int)(stateBytes / 16));

  k_lstm<<<192, 512, SMEM_BYTES, stream>>>(Xf, Wih0f, Whh0f, Wih1f, Whh1f,
                                           bsum0, bsum1, ring0c, ring1c, out);
}

// Round 9
// 9830.997 us; speedup vs baseline: 1.2089x; 1.0364x over previous
//
#include <hip/hip_runtime.h>
#include <math.h>

// ---------------------------------------------------------------------------
// 2-layer LSTM, B=64 T=512 I=256 H=768, fp32 in/out.
// Round 9: persistent kernel. Sync = r5 flag-detect + r8 tag-validated data.
//  - Producer: gate threads store u64 quanta [2xf16 | tag=t+1] (agent scope);
//    tid0 posts a per-WG flag AFTER the step barrier -- NO vmcnt ack. Flag is
//    a hint; embedded tags carry correctness.
//  - Consumer: poll ONLY dedicated 16B-strided flag lines (no data-line
//    ping-pong), then ONE u64 burst of all fragments, validate tags, rare
//    whole-burst retry.
// Weights in LDS. fp16 MFMA 16x16x32, fragment-major operands.
// ---------------------------------------------------------------------------

#define B_   64
#define T_   512
#define I_   256
#define H_   768
#define G4H  3072

constexpr size_t BTH = (size_t)B_ * T_ * H_;   // 25165824
constexpr size_t BH  = (size_t)B_ * H_;        // 49152

using f16_t = _Float16;
using f16x8 = __attribute__((ext_vector_type(8))) _Float16;
using f32x4 = __attribute__((ext_vector_type(4))) float;
typedef unsigned long long u64;

#define MFMA(a, b, c) __builtin_amdgcn_mfma_f32_16x16x32_f16((a), (b), (c), 0, 0, 0)

// Ring geometry: u64 quantum (ws, b, pair) at byte ((slot*96+ws)*64+b)*32 + pair*8.
#define SLOT_STRIDE 196608   // 96*64*32 bytes
#define RING_BYTES  (8 * SLOT_STRIDE)

// LDS partition (bytes): WL 0..98304 | pre 98304..132096 | bsL ..132224
#define SMEM_BYTES 132224

// ---------------------------------------------------------------------------
__global__ void k_packW(const float* __restrict__ src, f16_t* __restrict__ dst,
                        int K, int KC, int total) {
  int i = blockIdx.x * blockDim.x + threadIdx.x;
  int stride = gridDim.x * blockDim.x;
  for (; i < total; i += stride) {
    int e = i & 7;
    int lane = (i >> 3) & 63;
    int rest = i >> 9;          // ptile*KC + kc
    int kc = rest % KC;
    int ptile = rest / KC;
    int p = ptile * 16 + (lane & 15);
    int k = kc * 32 + (lane >> 4) * 8 + e;
    int r = (p & 3) * H_ + (p >> 2);
    dst[i] = (f16_t)src[(size_t)r * K + k];
  }
}

__global__ void k_packX(const float* __restrict__ x, f16_t* __restrict__ dst) {
  int i = blockIdx.x * blockDim.x + threadIdx.x;
  int stride = gridDim.x * blockDim.x;
  const int total = 4 * T_ * 8 * 64 * 8;  // 8,388,608
  for (; i < total; i += stride) {
    int e = i & 7;
    int lane = (i >> 3) & 63;
    int kc = (i >> 9) & 7;
    int t = (i >> 12) & 511;
    int mtile = i >> 21;
    int b = mtile * 16 + (lane & 15);
    int k = kc * 32 + (lane >> 4) * 8 + e;
    dst[i] = (f16_t)x[((size_t)b * T_ + t) * I_ + k];
  }
}

__global__ void k_bias(const float* __restrict__ bih, const float* __restrict__ bhh,
                       float* __restrict__ bsum) {
  int p = blockIdx.x * blockDim.x + threadIdx.x;
  if (p < G4H) {
    int r = (p & 3) * H_ + (p >> 2);
    bsum[p] = bih[r] + bhh[r];
  }
}

__global__ void k_zero(int4* __restrict__ d, int n) {
  int i = blockIdx.x * blockDim.x + threadIdx.x;
  if (i < n) d[i] = make_int4(0, 0, 0, 0);
}

__device__ __forceinline__ float sigf(float v) {
  return __builtin_amdgcn_rcpf(1.0f + __builtin_amdgcn_exp2f(v * -1.44269504f));
}
__device__ __forceinline__ float tanhf_fast(float v) {
  return 2.0f * __builtin_amdgcn_rcpf(1.0f + __builtin_amdgcn_exp2f(v * -2.88539008f)) - 1.0f;
}

__device__ __forceinline__ u64 ld_q(const u64* p) {
  return __hip_atomic_load(p, __ATOMIC_RELAXED, __HIP_MEMORY_SCOPE_AGENT);
}
__device__ __forceinline__ unsigned ld_flag(const int* p) {
  return (unsigned)__hip_atomic_load(p, __ATOMIC_RELAXED, __HIP_MEMORY_SCOPE_AGENT);
}

// Detect: lanes 0..N-1 poll dedicated flag lines (16B stride), exit when all
// carry tagv. Ping-pong is confined to these ~24 lines.
template <int N>
__device__ __forceinline__ void wait_flags(const int* f, unsigned tagv) {
  const int lane = threadIdx.x & 63;
  const int* p = f + lane * 4;
  for (;;) {
    unsigned v = (lane < N) ? ld_flag(p) : tagv;
    if (__all(v == tagv)) return;
    __builtin_amdgcn_s_sleep(1);
  }
}

// Full-96 check (ring-safety guard, off critical path).
__device__ __forceinline__ void wait96(const int* f, unsigned tagv) {
  const int lane = threadIdx.x & 63;
  for (;;) {
    unsigned v0 = ld_flag(f + lane * 4);
    unsigned v1 = (lane < 32) ? ld_flag(f + (64 + lane) * 4) : tagv;
    if (__all((v0 == tagv) & (v1 == tagv))) return;
    __builtin_amdgcn_s_sleep(2);
  }
}

// One combined burst: all A+B quanta (2*KCW chunks x 4 u64), validate every
// embedded tag (retry only while a laggard store is in flight), then
// convert + MFMA. Stale-tag safety: tag==tagv <=> that exact 8B store landed
// (slot tags 8 steps apart).
template <int KCW>
__device__ __forceinline__ void load2_mfma(const char* sb, const int (&bA)[KCW],
                                           const int (&bB)[KCW], unsigned tagv,
                                           const f16_t* wl0, const f16_t* wl1,
                                           f32x4& a00, f32x4& a01, f32x4& a10,
                                           f32x4& a11) {
  u64 v[2][KCW][4];
  for (;;) {
#pragma unroll
    for (int i = 0; i < KCW; ++i) {
      const u64* pA = (const u64*)(sb + bA[i]);
      const u64* pB = (const u64*)(sb + bB[i]);
#pragma unroll
      for (int w = 0; w < 4; ++w) {
        v[0][i][w] = ld_q(pA + w);
        v[1][i][w] = ld_q(pB + w);
      }
    }
    int ok = 1;
#pragma unroll
    for (int h = 0; h < 2; ++h)
#pragma unroll
      for (int i = 0; i < KCW; ++i)
#pragma unroll
        for (int w = 0; w < 4; ++w)
          ok &= (int)((unsigned)(v[h][i][w] >> 32) == tagv);
    if (__all(ok)) break;
    __builtin_amdgcn_s_sleep(2);
  }
#pragma unroll
  for (int i = 0; i < KCW; ++i) {
    union { unsigned u[4]; f16x8 f; } cA, cB;
#pragma unroll
    for (int w = 0; w < 4; ++w) {
      cA.u[w] = (unsigned)v[0][i][w];
      cB.u[w] = (unsigned)v[1][i][w];
    }
    f16x8 w0 = *(const f16x8*)(wl0 + (size_t)i * 512);
    f16x8 w1 = *(const f16x8*)(wl1 + (size_t)i * 512);
    a00 = MFMA(cA.f, w0, a00);
    a01 = MFMA(cA.f, w1, a01);
    a10 = MFMA(cB.f, w0, a10);
    a11 = MFMA(cB.f, w1, a11);
  }
}

// ---------------------------------------------------------------------------
// Persistent per-layer loop. 8 waves = mg(2) x kg(4); wave = 2x2 tile.
// L0: kg0 = x-GEMM (+ mg1: h1[t-8] ring-safety); kg1-3 consume h0[t-1]
//     (producer subsets (kg-1)*32..+32; union = all 96).
// L1: kg0-1 consume h0[t] (subsets kg*48..+48); kg2-3 consume h1[t-1]
//     (subsets (kg-2)*48..+48; union = all 96).
// Flags: flag[t*128 + ws] at 16B stride, value = t+1.
template <int KCW, bool IS_L1>
__device__ __forceinline__ void run_layer(
    int ws, const f16_t* __restrict__ Xf, const f16_t* __restrict__ Wihf,
    const f16_t* __restrict__ Whhf, const float* __restrict__ bsum,
    char* __restrict__ ring0c, char* __restrict__ ring1c,
    int* __restrict__ flag0, int* __restrict__ flag1,
    float* __restrict__ out, char* smem) {
  f16_t* WL = (f16_t*)smem;                              // [4 kg][2 p][KCW][512]
  float (*pre)[64][33] = (float (*)[64][33])(smem + 98304);
  float* bsL = (float*)(smem + 132096);                  // [32]

  const int tid = threadIdx.x;
  const int wave = tid >> 6, lane = tid & 63;
  const int kg = wave & 3, mg = wave >> 2;
  const int laneo = lane * 8;
  const int pt0 = ws * 2, m0 = mg * 2;
  const int l15 = lane & 15, l4 = lane >> 4;

  if (tid < 32) bsL[tid] = bsum[ws * 32 + tid];

  // ---- stage W into LDS (mg==0 waves) ----
  if (mg == 0) {
    const f16_t* src;
    int KC, kc0;
    if constexpr (!IS_L1) {
      if (kg == 0) { src = Wihf; KC = 8;  kc0 = 0; }
      else         { src = Whhf; KC = 24; kc0 = (kg - 1) * 8; }
    } else {
      if (kg < 2)  { src = Wihf; KC = 24; kc0 = kg * 12; }
      else         { src = Whhf; KC = 24; kc0 = (kg - 2) * 12; }
    }
#pragma unroll
    for (int p = 0; p < 2; ++p)
#pragma unroll
      for (int i = 0; i < KCW; ++i)
        *(uint4*)(WL + ((size_t)((kg * 2 + p) * KCW + i)) * 512 + laneo) =
            *(const uint4*)(src + ((size_t)(pt0 + p) * KC + kc0 + i) * 512 + laneo);
  }

  // Consumer chunk start (32-unit chunks of the source h vector).
  int kcs = 0;
  if constexpr (!IS_L1) kcs = (kg - 1) * 8;      // valid for kg>=1
  else                  kcs = (kg < 2) ? kg * 12 : (kg - 2) * 12;

  // Data byte offsets within a slot: chunk i, mtile m -> producer
  // ws'=(kcs+i)*4+l4, batch b = m*16+l15, pairs 0..3 contiguous (32B).
  int boffA[KCW], boffB[KCW];
#pragma unroll
  for (int i = 0; i < KCW; ++i) {
    boffA[i] = ((kcs + i) * 4 + l4) * 2048 + (m0 * 16 + l15) * 32;
    boffB[i] = boffA[i] + 512;   // mtile m0+1
  }
  const int fbase = kcs * 4;     // first producer ws' this wave depends on

  float c_reg = 0.f;
  const int u = tid & 7, b = tid >> 3;
  const int j = ws * 8 + u;
  char* myringc = IS_L1 ? ring1c : ring0c;
  int* myflag = IS_L1 ? flag1 : flag0;
  const f16_t* wl0 = WL + (size_t)(kg * 2) * KCW * 512 + laneo;
  const f16_t* wl1 = wl0 + (size_t)KCW * 512;

  __syncthreads();

  for (int t = 0; t < T_; ++t) {
    f32x4 a00 = {0.f, 0.f, 0.f, 0.f};
    f32x4 a01 = {0.f, 0.f, 0.f, 0.f};
    f32x4 a10 = {0.f, 0.f, 0.f, 0.f};
    f32x4 a11 = {0.f, 0.f, 0.f, 0.f};

    if constexpr (!IS_L1) {
      if (kg == 0) {
        // ring-safety: before this WG publishes h0[t] (over h0[t-8]'s slot),
        // all 96 L1 WGs must have completed step t-8 (flag1 == t-7), which
        // implies they consumed h0[t-8].
        if (mg == 1 && t >= 8)
          wait96(flag1 + (size_t)(t - 8) * 128 * 4, (unsigned)(t - 7));
        // x_t @ Wih0^T (no recurrence dependency)
        const f16_t* A0 = Xf + ((size_t)m0 * T_ + t) * 4096 + laneo;
        const f16_t* A1 = A0 + (size_t)T_ * 4096;
#pragma unroll
        for (int i = 0; i < KCW; ++i) {
          f16x8 x0 = *(const f16x8*)(A0 + (size_t)i * 512);
          f16x8 x1 = *(const f16x8*)(A1 + (size_t)i * 512);
          f16x8 w0 = *(const f16x8*)(wl0 + (size_t)i * 512);
          f16x8 w1 = *(const f16x8*)(wl1 + (size_t)i * 512);
          a00 = MFMA(x0, w0, a00);
          a01 = MFMA(x0, w1, a01);
          a10 = MFMA(x1, w0, a10);
          a11 = MFMA(x1, w1, a11);
        }
      } else if (t >= 1) {
        wait_flags<32>(flag0 + ((size_t)(t - 1) * 128 + fbase) * 4, (unsigned)t);
        const char* sb = ring0c + (size_t)((t - 1) & 7) * SLOT_STRIDE;
        load2_mfma<KCW>(sb, boffA, boffB, (unsigned)t, wl0, wl1, a00, a01, a10, a11);
      }
    } else {
      const int srcstep = (kg < 2) ? t : t - 1;
      if (srcstep >= 0) {
        const unsigned tg = (unsigned)(srcstep + 1);
        int* fl = (kg < 2) ? flag0 : flag1;
        wait_flags<48>(fl + ((size_t)srcstep * 128 + fbase) * 4, tg);
        const char* sb = ((kg < 2) ? ring0c : ring1c) +
                         (size_t)(srcstep & 7) * SLOT_STRIDE;
        load2_mfma<KCW>(sb, boffA, boffB, tg, wl0, wl1, a00, a01, a10, a11);
      }
    }

    // ---- partial-sum exchange (C layout: col=lane&15, row=l4*4+r) ----
#pragma unroll
    for (int r = 0; r < 4; ++r) {
      pre[kg][m0 * 16 + l4 * 4 + r][l15]           = a00[r];
      pre[kg][m0 * 16 + l4 * 4 + r][16 + l15]      = a01[r];
      pre[kg][m0 * 16 + 16 + l4 * 4 + r][l15]      = a10[r];
      pre[kg][m0 * 16 + 16 + l4 * 4 + r][16 + l15] = a11[r];
    }
    __syncthreads();

    // ---- gate phase: thread = (u = tid&7, b = tid>>3) ----
    {
      float g0 = pre[0][b][4 * u + 0] + pre[1][b][4 * u + 0] + pre[2][b][4 * u + 0] + pre[3][b][4 * u + 0] + bsL[4 * u + 0];
      float g1 = pre[0][b][4 * u + 1] + pre[1][b][4 * u + 1] + pre[2][b][4 * u + 1] + pre[3][b][4 * u + 1] + bsL[4 * u + 1];
      float g2 = pre[0][b][4 * u + 2] + pre[1][b][4 * u + 2] + pre[2][b][4 * u + 2] + pre[3][b][4 * u + 2] + bsL[4 * u + 2];
      float g3 = pre[0][b][4 * u + 3] + pre[1][b][4 * u + 3] + pre[2][b][4 * u + 3] + pre[3][b][4 * u + 3] + bsL[4 * u + 3];
      float ig = sigf(g0), fg = sigf(g1), gg = tanhf_fast(g2), og = sigf(g3);
      c_reg = fg * c_reg + ig * gg;
      float h = og * tanhf_fast(c_reg);

      // publish FIRST (critical path): even-u threads store one u64 quantum
      // [h(u) | h(u+1) | tag=t+1] with a single co-atomic relaxed store.
      unsigned hb = (unsigned)__builtin_bit_cast(unsigned short, (f16_t)h);
      unsigned nb = (unsigned)__shfl((int)hb, lane + 1);
      if ((u & 1) == 0) {
        u64 val = (u64)(hb | (nb << 16)) | ((u64)(unsigned)(t + 1) << 32);
        u64* dst = (u64*)(myringc + (size_t)(t & 7) * SLOT_STRIDE +
                          (size_t)ws * 2048 + (size_t)b * 32 + (u >> 1) * 8);
        __hip_atomic_store(dst, val, __ATOMIC_RELAXED, __HIP_MEMORY_SCOPE_AGENT);
      }

      if constexpr (IS_L1) {
        out[((size_t)b * T_ + t) * H_ + j] = h;  // ys
        if (t == T_ - 1) {
          out[BTH + BH + (size_t)b * H_ + j] = h;
          out[BTH + 3 * BH + (size_t)b * H_ + j] = c_reg;
        }
      } else {
        if (t == T_ - 1) {
          out[BTH + (size_t)b * H_ + j] = h;
          out[BTH + 2 * BH + (size_t)b * H_ + j] = c_reg;
        }
      }
    }
    __syncthreads();   // all quanta of step t issued; pre[] safe for t+1

    // flag hint (no vmcnt ack -- consumers validate embedded tags).
    if (tid == 0)
      __hip_atomic_store(myflag + ((size_t)t * 128 + ws) * 4, t + 1,
                         __ATOMIC_RELAXED, __HIP_MEMORY_SCOPE_AGENT);
  }
}

__launch_bounds__(512, 1)
__global__ void k_lstm(const f16_t* __restrict__ Xf,
                       const f16_t* __restrict__ Wih0f, const f16_t* __restrict__ Whh0f,
                       const f16_t* __restrict__ Wih1f, const f16_t* __restrict__ Whh1f,
                       const float* __restrict__ bsum0, const float* __restrict__ bsum1,
                       char* __restrict__ ring0c, char* __restrict__ ring1c,
                       int* __restrict__ flag0, int* __restrict__ flag1,
                       float* __restrict__ out) {
  extern __shared__ char smem[];
  const int wg = blockIdx.x;
  if (wg < 96)
    run_layer<8, false>(wg, Xf, Wih0f, Whh0f, bsum0, ring0c, ring1c, flag0, flag1, out, smem);
  else
    run_layer<12, true>(wg - 96, Xf, Wih1f, Whh1f, bsum1, ring0c, ring1c, flag0, flag1, out, smem);
}

// ---------------------------------------------------------------------------
extern "C" void kernel_launch(void* const* d_in, const int* in_sizes, int n_in,
                              void* d_out, int out_size, void* d_ws, size_t ws_size,
                              hipStream_t stream) {
  const float* x    = (const float*)d_in[0];
  const float* wih0 = (const float*)d_in[1];
  const float* whh0 = (const float*)d_in[2];
  const float* bih0 = (const float*)d_in[3];
  const float* bhh0 = (const float*)d_in[4];
  const float* wih1 = (const float*)d_in[5];
  const float* whh1 = (const float*)d_in[6];
  const float* bih1 = (const float*)d_in[7];
  const float* bhh1 = (const float*)d_in[8];
  float* out = (float*)d_out;

  char* base = (char*)d_ws;
  size_t off = 0;
  auto take = [&](size_t bytes) -> char* {
    char* r = base + off;
    off = (off + bytes + 255) & ~(size_t)255;
    return r;
  };
  f16_t* Wih0f = (f16_t*)take((size_t)G4H * I_ * 2);
  f16_t* Whh0f = (f16_t*)take((size_t)G4H * H_ * 2);
  f16_t* Wih1f = (f16_t*)take((size_t)G4H * H_ * 2);
  f16_t* Whh1f = (f16_t*)take((size_t)G4H * H_ * 2);
  f16_t* Xf    = (f16_t*)take((size_t)4 * T_ * 8 * 64 * 8 * 2);
  float* bsum0 = (float*)take((size_t)G4H * 4);
  float* bsum1 = (float*)take((size_t)G4H * 4);
  // state (zeroed each call): 2 tagged rings + 2 flag arrays [T][128]x16B
  const size_t flagBytes = (size_t)T_ * 128 * 16;        // 1 MB each
  const size_t stateBytes = 2 * (size_t)RING_BYTES + 2 * flagBytes;
  char* st = take(stateBytes);
  char* ring0c = st;
  char* ring1c = st + RING_BYTES;
  int* flag0 = (int*)(st + 2 * (size_t)RING_BYTES);
  int* flag1 = flag0 + (size_t)T_ * 128 * 4;

  hipFuncSetAttribute(reinterpret_cast<const void*>(k_lstm),
                      hipFuncAttributeMaxDynamicSharedMemorySize, SMEM_BYTES);

  k_packW<<<768, 256, 0, stream>>>(wih0, Wih0f, I_, 8, G4H * I_);
  k_packW<<<2048, 256, 0, stream>>>(whh0, Whh0f, H_, 24, G4H * H_);
  k_packW<<<2048, 256, 0, stream>>>(wih1, Wih1f, H_, 24, G4H * H_);
  k_packW<<<2048, 256, 0, stream>>>(whh1, Whh1f, H_, 24, G4H * H_);
  k_packX<<<4096, 256, 0, stream>>>(x, Xf);
  k_bias<<<12, 256, 0, stream>>>(bih0, bhh0, bsum0);
  k_bias<<<12, 256, 0, stream>>>(bih1, bhh1, bsum1);
  k_zero<<<1280, 256, 0, stream>>>((int4*)st, (int)(stateBytes / 16));

  k_lstm<<<192, 512, SMEM_BYTES, stream>>>(Xf, Wih0f, Whh0f, Wih1f, Whh1f,
                                           bsum0, bsum1, ring0c, ring1c,
                                           flag0, flag1, out);
}

// Round 10
// 2736.166 us; speedup vs baseline: 4.3434x; 3.5930x over previous
//
#include <hip/hip_runtime.h>
#include <math.h>

// ---------------------------------------------------------------------------
// 2-layer LSTM, B=64 T=512 I=256 H=768, fp32 in/out.
// Round 10: r5's proven sync discipline (narrow ack'd flags, one-shot data)
// with a shortened producer path:
//  - gate threads store 4-unit u64 ring quanta DIRECTLY (no LDS re-gather);
//  - each wave acks its own stores with vmcnt(0) in parallel; sync; tid0 flag;
//  - ys/out stores deferred until after the flag post (off critical path);
//  - consumers: poll dedicated 16B-strided flag lines, then ONE u64 burst
//    (no tags, no retries -- flags are ack'd).
// Weights in LDS. fp16 MFMA 16x16x32, fragment-major operands.
// ---------------------------------------------------------------------------

#define B_   64
#define T_   512
#define I_   256
#define H_   768
#define G4H  3072

constexpr size_t BTH = (size_t)B_ * T_ * H_;   // 25165824
constexpr size_t BH  = (size_t)B_ * H_;        // 49152

using f16_t = _Float16;
using f16x8 = __attribute__((ext_vector_type(8))) _Float16;
using f32x4 = __attribute__((ext_vector_type(4))) float;
typedef unsigned long long u64;

#define MFMA(a, b, c) __builtin_amdgcn_mfma_f32_16x16x32_f16((a), (b), (c), 0, 0, 0)

// Ring: quantum u64 = 4 f16 units. addr = slot*98304 + ws*1024 + q*512 + b*8,
// q in {0,1} selects units ws*8+4q .. +4q+3.
#define SLOT_STRIDE 98304    // 96*64*16 bytes
#define RING_BYTES  (8 * SLOT_STRIDE)

// LDS partition (bytes): WL 0..98304 | pre 98304..132096 | bsL ..132224
#define SMEM_BYTES 132224

// ---------------------------------------------------------------------------
__global__ void k_packW(const float* __restrict__ src, f16_t* __restrict__ dst,
                        int K, int KC, int total) {
  int i = blockIdx.x * blockDim.x + threadIdx.x;
  int stride = gridDim.x * blockDim.x;
  for (; i < total; i += stride) {
    int e = i & 7;
    int lane = (i >> 3) & 63;
    int rest = i >> 9;          // ptile*KC + kc
    int kc = rest % KC;
    int ptile = rest / KC;
    int p = ptile * 16 + (lane & 15);
    int k = kc * 32 + (lane >> 4) * 8 + e;
    int r = (p & 3) * H_ + (p >> 2);
    dst[i] = (f16_t)src[(size_t)r * K + k];
  }
}

__global__ void k_packX(const float* __restrict__ x, f16_t* __restrict__ dst) {
  int i = blockIdx.x * blockDim.x + threadIdx.x;
  int stride = gridDim.x * blockDim.x;
  const int total = 4 * T_ * 8 * 64 * 8;  // 8,388,608
  for (; i < total; i += stride) {
    int e = i & 7;
    int lane = (i >> 3) & 63;
    int kc = (i >> 9) & 7;
    int t = (i >> 12) & 511;
    int mtile = i >> 21;
    int b = mtile * 16 + (lane & 15);
    int k = kc * 32 + (lane >> 4) * 8 + e;
    dst[i] = (f16_t)x[((size_t)b * T_ + t) * I_ + k];
  }
}

__global__ void k_bias(const float* __restrict__ bih, const float* __restrict__ bhh,
                       float* __restrict__ bsum) {
  int p = blockIdx.x * blockDim.x + threadIdx.x;
  if (p < G4H) {
    int r = (p & 3) * H_ + (p >> 2);
    bsum[p] = bih[r] + bhh[r];
  }
}

__global__ void k_zero(int4* __restrict__ d, int n) {
  int i = blockIdx.x * blockDim.x + threadIdx.x;
  if (i < n) d[i] = make_int4(0, 0, 0, 0);
}

__device__ __forceinline__ float sigf(float v) {
  return __builtin_amdgcn_rcpf(1.0f + __builtin_amdgcn_exp2f(v * -1.44269504f));
}
__device__ __forceinline__ float tanhf_fast(float v) {
  return 2.0f * __builtin_amdgcn_rcpf(1.0f + __builtin_amdgcn_exp2f(v * -2.88539008f)) - 1.0f;
}

__device__ __forceinline__ u64 ld_q(const u64* p) {
  return __hip_atomic_load(p, __ATOMIC_RELAXED, __HIP_MEMORY_SCOPE_AGENT);
}
__device__ __forceinline__ unsigned ld_flag(const int* p) {
  return (unsigned)__hip_atomic_load(p, __ATOMIC_RELAXED, __HIP_MEMORY_SCOPE_AGENT);
}

// Detect: lanes 0..N-1 poll dedicated flag lines (16B stride).
template <int N>
__device__ __forceinline__ void wait_flags(const int* f, unsigned tagv) {
  const int lane = threadIdx.x & 63;
  const int* p = f + lane * 4;
  for (;;) {
    unsigned v = (lane < N) ? ld_flag(p) : tagv;
    if (__all(v == tagv)) return;
    __builtin_amdgcn_s_sleep(1);
  }
}

// Full-96 check (ring-safety guard, off critical path).
__device__ __forceinline__ void wait96(const int* f, unsigned tagv) {
  const int lane = threadIdx.x & 63;
  for (;;) {
    unsigned v0 = ld_flag(f + lane * 4);
    unsigned v1 = (lane < 32) ? ld_flag(f + (64 + lane) * 4) : tagv;
    if (__all((v0 == tagv) & (v1 == tagv))) return;
    __builtin_amdgcn_s_sleep(2);
  }
}

// One-shot burst (flag-guaranteed): per chunk i load q0,q1 for both mtiles,
// assemble f16x8 fragments, MFMA.
template <int KCW>
__device__ __forceinline__ void load_mfma(const char* sb, const int (&bA)[KCW],
                                          const f16_t* wl0, const f16_t* wl1,
                                          f32x4& a00, f32x4& a01, f32x4& a10,
                                          f32x4& a11) {
  u64 vA[KCW][2], vB[KCW][2];
#pragma unroll
  for (int i = 0; i < KCW; ++i) {
    const u64* p = (const u64*)(sb + bA[i]);
    vA[i][0] = ld_q(p);        // q0, mtile m0
    vA[i][1] = ld_q(p + 64);   // q1 (+512B)
    vB[i][0] = ld_q(p + 16);   // q0, mtile m0+1 (+128B)
    vB[i][1] = ld_q(p + 80);   // q1, mtile m0+1
  }
#pragma unroll
  for (int i = 0; i < KCW; ++i) {
    union { u64 q[2]; f16x8 f; } cA, cB;
    cA.q[0] = vA[i][0]; cA.q[1] = vA[i][1];
    cB.q[0] = vB[i][0]; cB.q[1] = vB[i][1];
    f16x8 w0 = *(const f16x8*)(wl0 + (size_t)i * 512);
    f16x8 w1 = *(const f16x8*)(wl1 + (size_t)i * 512);
    a00 = MFMA(cA.f, w0, a00);
    a01 = MFMA(cA.f, w1, a01);
    a10 = MFMA(cB.f, w0, a10);
    a11 = MFMA(cB.f, w1, a11);
  }
}

// ---------------------------------------------------------------------------
// Persistent per-layer loop. 8 waves = mg(2) x kg(4); wave = 2x2 tile.
// L0: kg0 = x-GEMM (+ mg1: ring-safety wait96); kg1-3 consume h0[t-1]
//     (32-producer subsets; union = 96). L1: kg0-1 consume h0[t], kg2-3
//     consume h1[t-1] (48-producer subsets; unions = 96 each).
// Intra-layer skew <= 1 step (every WG waits on its whole layer) => depth-8
// self-reuse safe; L0-vs-L1 run-ahead bounded by wait96 on h1[t-8].
template <int KCW, bool IS_L1>
__device__ __forceinline__ void run_layer(
    int ws, const f16_t* __restrict__ Xf, const f16_t* __restrict__ Wihf,
    const f16_t* __restrict__ Whhf, const float* __restrict__ bsum,
    char* __restrict__ ring0c, char* __restrict__ ring1c,
    int* __restrict__ flag0, int* __restrict__ flag1,
    float* __restrict__ out, char* smem) {
  f16_t* WL = (f16_t*)smem;                              // [4 kg][2 p][KCW][512]
  float (*pre)[64][33] = (float (*)[64][33])(smem + 98304);
  float* bsL = (float*)(smem + 132096);                  // [32]

  const int tid = threadIdx.x;
  const int wave = tid >> 6, lane = tid & 63;
  const int kg = wave & 3, mg = wave >> 2;
  const int laneo = lane * 8;
  const int pt0 = ws * 2, m0 = mg * 2;
  const int l15 = lane & 15, l4 = lane >> 4;

  if (tid < 32) bsL[tid] = bsum[ws * 32 + tid];

  // ---- stage W into LDS (mg==0 waves) ----
  if (mg == 0) {
    const f16_t* src;
    int KC, kc0;
    if constexpr (!IS_L1) {
      if (kg == 0) { src = Wihf; KC = 8;  kc0 = 0; }
      else         { src = Whhf; KC = 24; kc0 = (kg - 1) * 8; }
    } else {
      if (kg < 2)  { src = Wihf; KC = 24; kc0 = kg * 12; }
      else         { src = Whhf; KC = 24; kc0 = (kg - 2) * 12; }
    }
#pragma unroll
    for (int p = 0; p < 2; ++p)
#pragma unroll
      for (int i = 0; i < KCW; ++i)
        *(uint4*)(WL + ((size_t)((kg * 2 + p) * KCW + i)) * 512 + laneo) =
            *(const uint4*)(src + ((size_t)(pt0 + p) * KC + kc0 + i) * 512 + laneo);
  }

  // Consumer chunk start (32-unit chunks of the source h vector).
  int kcs = 0;
  if constexpr (!IS_L1) kcs = (kg - 1) * 8;      // valid for kg>=1
  else                  kcs = (kg < 2) ? kg * 12 : (kg - 2) * 12;

  // Byte offset of chunk i's base quantum: producer ws'=(kcs+i)*4+l4,
  // batch row = m0*16+l15.
  int bA[KCW];
#pragma unroll
  for (int i = 0; i < KCW; ++i)
    bA[i] = ((kcs + i) * 4 + l4) * 1024 + (m0 * 16 + l15) * 8;
  const int fbase = kcs * 4;     // first producer ws' this wave depends on

  float c_reg = 0.f;
  const int u = tid & 7, b = tid >> 3;
  const int j = ws * 8 + u;
  char* myringc = IS_L1 ? ring1c : ring0c;
  int* myflag = IS_L1 ? flag1 : flag0;
  const f16_t* wl0 = WL + (size_t)(kg * 2) * KCW * 512 + laneo;
  const f16_t* wl1 = wl0 + (size_t)KCW * 512;

  __syncthreads();

  for (int t = 0; t < T_; ++t) {
    f32x4 a00 = {0.f, 0.f, 0.f, 0.f};
    f32x4 a01 = {0.f, 0.f, 0.f, 0.f};
    f32x4 a10 = {0.f, 0.f, 0.f, 0.f};
    f32x4 a11 = {0.f, 0.f, 0.f, 0.f};

    if constexpr (!IS_L1) {
      if (kg == 0) {
        // ring-safety: before this WG publishes h0[t] (over h0[t-8]'s slot),
        // all 96 L1 WGs must have completed step t-8 (which implies they
        // consumed h0[t-8]).
        if (mg == 1 && t >= 8)
          wait96(flag1 + (size_t)(t - 8) * 128 * 4, (unsigned)(t - 7));
        // x_t @ Wih0^T (no recurrence dependency)
        const f16_t* A0 = Xf + ((size_t)m0 * T_ + t) * 4096 + laneo;
        const f16_t* A1 = A0 + (size_t)T_ * 4096;
#pragma unroll
        for (int i = 0; i < KCW; ++i) {
          f16x8 x0 = *(const f16x8*)(A0 + (size_t)i * 512);
          f16x8 x1 = *(const f16x8*)(A1 + (size_t)i * 512);
          f16x8 w0 = *(const f16x8*)(wl0 + (size_t)i * 512);
          f16x8 w1 = *(const f16x8*)(wl1 + (size_t)i * 512);
          a00 = MFMA(x0, w0, a00);
          a01 = MFMA(x0, w1, a01);
          a10 = MFMA(x1, w0, a10);
          a11 = MFMA(x1, w1, a11);
        }
      } else if (t >= 1) {
        wait_flags<32>(flag0 + ((size_t)(t - 1) * 128 + fbase) * 4, (unsigned)t);
        const char* sb = ring0c + (size_t)((t - 1) & 7) * SLOT_STRIDE;
        load_mfma<KCW>(sb, bA, wl0, wl1, a00, a01, a10, a11);
      }
    } else {
      const int srcstep = (kg < 2) ? t : t - 1;
      if (srcstep >= 0) {
        const unsigned tg = (unsigned)(srcstep + 1);
        int* fl = (kg < 2) ? flag0 : flag1;
        wait_flags<48>(fl + ((size_t)srcstep * 128 + fbase) * 4, tg);
        const char* sb = ((kg < 2) ? ring0c : ring1c) +
                         (size_t)(srcstep & 7) * SLOT_STRIDE;
        load_mfma<KCW>(sb, bA, wl0, wl1, a00, a01, a10, a11);
      }
    }

    // ---- partial-sum exchange (C layout: col=lane&15, row=l4*4+r) ----
#pragma unroll
    for (int r = 0; r < 4; ++r) {
      pre[kg][m0 * 16 + l4 * 4 + r][l15]           = a00[r];
      pre[kg][m0 * 16 + l4 * 4 + r][16 + l15]      = a01[r];
      pre[kg][m0 * 16 + 16 + l4 * 4 + r][l15]      = a10[r];
      pre[kg][m0 * 16 + 16 + l4 * 4 + r][16 + l15] = a11[r];
    }
    __syncthreads();

    // ---- gate phase: thread = (u = tid&7, b = tid>>3) ----
    float h;
    {
      float g0 = pre[0][b][4 * u + 0] + pre[1][b][4 * u + 0] + pre[2][b][4 * u + 0] + pre[3][b][4 * u + 0] + bsL[4 * u + 0];
      float g1 = pre[0][b][4 * u + 1] + pre[1][b][4 * u + 1] + pre[2][b][4 * u + 1] + pre[3][b][4 * u + 1] + bsL[4 * u + 1];
      float g2 = pre[0][b][4 * u + 2] + pre[1][b][4 * u + 2] + pre[2][b][4 * u + 2] + pre[3][b][4 * u + 2] + bsL[4 * u + 2];
      float g3 = pre[0][b][4 * u + 3] + pre[1][b][4 * u + 3] + pre[2][b][4 * u + 3] + pre[3][b][4 * u + 3] + bsL[4 * u + 3];
      float ig = sigf(g0), fg = sigf(g1), gg = tanhf_fast(g2), og = sigf(g3);
      c_reg = fg * c_reg + ig * gg;
      h = og * tanhf_fast(c_reg);

      // ring publish: gather 4 units via shfl, u%4==0 stores one u64 quantum.
      unsigned hb = (unsigned)__builtin_bit_cast(unsigned short, (f16_t)h);
      unsigned n1 = (unsigned)__shfl((int)hb, lane + 1);
      unsigned n2 = (unsigned)__shfl((int)hb, lane + 2);
      unsigned n3 = (unsigned)__shfl((int)hb, lane + 3);
      if ((u & 3) == 0) {
        u64 val = (u64)(hb | (n1 << 16)) | ((u64)(n2 | (n3 << 16)) << 32);
        u64* dst = (u64*)(myringc + (size_t)(t & 7) * SLOT_STRIDE +
                          (size_t)ws * 1024 + (u >> 2) * 512 + (size_t)b * 8);
        __hip_atomic_store(dst, val, __ATOMIC_RELAXED, __HIP_MEMORY_SCOPE_AGENT);
      }
    }
    // per-wave ack of own ring stores (parallel across waves), then publish.
    asm volatile("s_waitcnt vmcnt(0)" ::: "memory");
    __syncthreads();
    if (tid == 0)
      __hip_atomic_store(myflag + ((size_t)t * 128 + ws) * 4, t + 1,
                         __ATOMIC_RELAXED, __HIP_MEMORY_SCOPE_AGENT);

    // ---- deferred outputs (off critical path) ----
    if constexpr (IS_L1) {
      out[((size_t)b * T_ + t) * H_ + j] = h;  // ys
      if (t == T_ - 1) {
        out[BTH + BH + (size_t)b * H_ + j] = h;
        out[BTH + 3 * BH + (size_t)b * H_ + j] = c_reg;
      }
    } else {
      if (t == T_ - 1) {
        out[BTH + (size_t)b * H_ + j] = h;
        out[BTH + 2 * BH + (size_t)b * H_ + j] = c_reg;
      }
    }
  }
}

__launch_bounds__(512, 1)
__global__ void k_lstm(const f16_t* __restrict__ Xf,
                       const f16_t* __restrict__ Wih0f, const f16_t* __restrict__ Whh0f,
                       const f16_t* __restrict__ Wih1f, const f16_t* __restrict__ Whh1f,
                       const float* __restrict__ bsum0, const float* __restrict__ bsum1,
                       char* __restrict__ ring0c, char* __restrict__ ring1c,
                       int* __restrict__ flag0, int* __restrict__ flag1,
                       float* __restrict__ out) {
  extern __shared__ char smem[];
  const int wg = blockIdx.x;
  if (wg < 96)
    run_layer<8, false>(wg, Xf, Wih0f, Whh0f, bsum0, ring0c, ring1c, flag0, flag1, out, smem);
  else
    run_layer<12, true>(wg - 96, Xf, Wih1f, Whh1f, bsum1, ring0c, ring1c, flag0, flag1, out, smem);
}

// ---------------------------------------------------------------------------
extern "C" void kernel_launch(void* const* d_in, const int* in_sizes, int n_in,
                              void* d_out, int out_size, void* d_ws, size_t ws_size,
                              hipStream_t stream) {
  const float* x    = (const float*)d_in[0];
  const float* wih0 = (const float*)d_in[1];
  const float* whh0 = (const float*)d_in[2];
  const float* bih0 = (const float*)d_in[3];
  const float* bhh0 = (const float*)d_in[4];
  const float* wih1 = (const float*)d_in[5];
  const float* whh1 = (const float*)d_in[6];
  const float* bih1 = (const float*)d_in[7];
  const float* bhh1 = (const float*)d_in[8];
  float* out = (float*)d_out;

  char* base = (char*)d_ws;
  size_t off = 0;
  auto take = [&](size_t bytes) -> char* {
    char* r = base + off;
    off = (off + bytes + 255) & ~(size_t)255;
    return r;
  };
  f16_t* Wih0f = (f16_t*)take((size_t)G4H * I_ * 2);
  f16_t* Whh0f = (f16_t*)take((size_t)G4H * H_ * 2);
  f16_t* Wih1f = (f16_t*)take((size_t)G4H * H_ * 2);
  f16_t* Whh1f = (f16_t*)take((size_t)G4H * H_ * 2);
  f16_t* Xf    = (f16_t*)take((size_t)4 * T_ * 8 * 64 * 8 * 2);
  float* bsum0 = (float*)take((size_t)G4H * 4);
  float* bsum1 = (float*)take((size_t)G4H * 4);
  // rings (no zero-init needed: flag-gated) + flags [T][128]x16B (zeroed)
  char* ring0c = take(RING_BYTES);
  char* ring1c = take(RING_BYTES);
  const size_t flagBytes = (size_t)T_ * 128 * 16;        // 1 MB each
  char* fl = take(2 * flagBytes);
  int* flag0 = (int*)fl;
  int* flag1 = flag0 + (size_t)T_ * 128 * 4;

  hipFuncSetAttribute(reinterpret_cast<const void*>(k_lstm),
                      hipFuncAttributeMaxDynamicSharedMemorySize, SMEM_BYTES);

  k_packW<<<768, 256, 0, stream>>>(wih0, Wih0f, I_, 8, G4H * I_);
  k_packW<<<2048, 256, 0, stream>>>(whh0, Whh0f, H_, 24, G4H * H_);
  k_packW<<<2048, 256, 0, stream>>>(wih1, Wih1f, H_, 24, G4H * H_);
  k_packW<<<2048, 256, 0, stream>>>(whh1, Whh1f, H_, 24, G4H * H_);
  k_packX<<<4096, 256, 0, stream>>>(x, Xf);
  k_bias<<<12, 256, 0, stream>>>(bih0, bhh0, bsum0);
  k_bias<<<12, 256, 0, stream>>>(bih1, bhh1, bsum1);
  k_zero<<<512, 256, 0, stream>>>((int4*)fl, (int)(2 * flagBytes / 16));

  k_lstm<<<192, 512, SMEM_BYTES, stream>>>(Xf, Wih0f, Whh0f, Wih1f, Whh1f,
                                           bsum0, bsum1, ring0c, ring1c,
                                           flag0, flag1, out);
}